// Round 6
// baseline (43.460 us; speedup 1.0000x reference)
//
#include <hip/hip_runtime.h>
#include <hip/hip_bf16.h>

typedef __attribute__((ext_vector_type(8))) short bf16x8;
typedef __attribute__((ext_vector_type(4))) float f32x4;

#define NPIX 6272          // 2*56*56
#define HW 56
#define HEADS 8
#define HD 32
#define KW 7
#define DIM 256
#define UK 112             // union keys: 8 rows x 14 cols
#define UKP 128            // padded keys
#define NX (NPIX * DIM)    // 1605632
#define NW (DIM * DIM)     // 65536

__device__ inline short f2bf(float f) {
    __hip_bfloat16 h = __float2bfloat16(f);
    return *(short*)&h;
}

// ---------------- f32 -> bf16 conversion pre-pass ---------------------------
__global__ __launch_bounds__(256) void cvt_kernel(
    const float* __restrict__ X,
    const float* __restrict__ Wq, const float* __restrict__ Wk, const float* __restrict__ Wv,
    short* __restrict__ Xb, short* __restrict__ Wqb,
    short* __restrict__ Wkb, short* __restrict__ Wvb)
{
    const size_t e0 = ((size_t)blockIdx.x * 256 + threadIdx.x) * 8;
    const float* src; short* dst; size_t off;
    if (e0 < NX)                { src = X;  dst = Xb;  off = e0; }
    else if (e0 < NX + NW)      { src = Wq; dst = Wqb; off = e0 - NX; }
    else if (e0 < NX + 2 * NW)  { src = Wk; dst = Wkb; off = e0 - NX - NW; }
    else                        { src = Wv; dst = Wvb; off = e0 - NX - 2 * NW; }
    float4 f0 = *(const float4*)(src + off);
    float4 f1 = *(const float4*)(src + off + 4);
    bf16x8 v;
    v[0]=f2bf(f0.x); v[1]=f2bf(f0.y); v[2]=f2bf(f0.z); v[3]=f2bf(f0.w);
    v[4]=f2bf(f1.x); v[5]=f2bf(f1.y); v[6]=f2bf(f1.z); v[7]=f2bf(f1.w);
    *(bf16x8*)(dst + off) = v;
}

// ---------------- Projection GEMM (bf16 in): Y = X @ W^T + b (* scale) ------
__global__ __launch_bounds__(256) void proj_kernel(
    const short* __restrict__ Xb,
    const short* __restrict__ Wqb, const short* __restrict__ Wkb, const short* __restrict__ Wvb,
    const float* __restrict__ Bq, const float* __restrict__ Bk, const float* __restrict__ Bv,
    __hip_bfloat16* __restrict__ Qo, __hip_bfloat16* __restrict__ Ko, __hip_bfloat16* __restrict__ Vo)
{
    __shared__ short Wsh[64 * 256];   // 32KB, byte ^= ((col&31)<<4)

    const int tid  = threadIdx.x;
    const int wave = tid >> 6;
    const int lane = tid & 63;
    const int l15  = lane & 15;
    const int hi   = lane >> 4;

    const short* W; const float* Bi; __hip_bfloat16* Y; float scale;
    if (blockIdx.z == 0)      { W = Wqb; Bi = Bq; Y = Qo; scale = 0.17677669529663687f; }
    else if (blockIdx.z == 1) { W = Wkb; Bi = Bk; Y = Ko; scale = 1.0f; }
    else                      { W = Wvb; Bi = Bv; Y = Vo; scale = 1.0f; }

    {   // stage W slice [64 cols][256 k] swizzled
        const int col = tid >> 2;
        const int k0  = (tid & 3) * 64;
        const short* src = W + (size_t)(blockIdx.y * 64 + col) * DIM + k0;
        char* row = (char*)Wsh + col * 512;
        const int swz = (col & 31) << 4;
        #pragma unroll
        for (int m = 0; m < 8; ++m) {
            bf16x8 v = *(const bf16x8*)(src + m * 8);
            *(bf16x8*)(row + ((2 * (k0 + m * 8)) ^ swz)) = v;
        }
    }
    __syncthreads();

    const short* xrow = Xb + (size_t)(blockIdx.x * 64 + wave * 16 + l15) * DIM;

    f32x4 acc[4];
    #pragma unroll
    for (int c = 0; c < 4; ++c) acc[c] = (f32x4){0.f, 0.f, 0.f, 0.f};

    #pragma unroll
    for (int kk = 0; kk < 8; ++kk) {
        bf16x8 a = *(const bf16x8*)(xrow + kk * 32 + hi * 8);
        #pragma unroll
        for (int c = 0; c < 4; ++c) {
            const int col = c * 16 + l15;
            bf16x8 b = *(const bf16x8*)((char*)Wsh + col * 512 +
                                        ((kk * 64 + hi * 16) ^ ((col & 31) << 4)));
            acc[c] = __builtin_amdgcn_mfma_f32_16x16x32_bf16(a, b, acc[c], 0, 0, 0);
        }
    }

    #pragma unroll
    for (int c = 0; c < 4; ++c) {
        const int col = blockIdx.y * 64 + c * 16 + l15;
        const float bvv = Bi[col];
        #pragma unroll
        for (int r = 0; r < 4; ++r) {
            const int row = blockIdx.x * 64 + wave * 16 + hi * 4 + r;
            Y[(size_t)row * DIM + col] = __float2bfloat16((acc[c][r] + bvv) * scale);
        }
    }
}

// ---------------- Neighborhood attention, MFMA-tiled, head-split ------------
// block = (jt, ip|hg, b): 16 pixels x 4 heads (hg picks heads 4hg..4hg+3);
// wave wv owns head hg*4+wv. Key union 8x14=112 (pad 128).
// VshT[128 dims][128 keys] transposed+swizzled (32KB) + Psh (16KB) = 48KB
// -> 3 blocks/CU. Q/K frags prefetched from global before staging barrier.
__global__ __launch_bounds__(256, 3) void nattn_kernel(
    const __hip_bfloat16* __restrict__ Qg,   // [NPIX][256] bf16 ws
    const __hip_bfloat16* __restrict__ Kg,
    const __hip_bfloat16* __restrict__ Vg,
    const float* __restrict__ rpb,           // [8][13][13] f32
    float* __restrict__ out)                 // [NPIX][256] f32
{
    __shared__ short VshT[128 * UKP];        // 32768 B: [d'][key], byte ^= ((d'&7)<<4)
    __shared__ short Psh[4 * 16 * UKP];      // 16384 B: byte ^= (pix<<4)

    const int tid  = threadIdx.x;
    const int wv   = tid >> 6;
    const int lane = tid & 63;
    const int l15  = lane & 15;
    const int hi   = lane >> 4;

    const int jt = blockIdx.x;               // 0..6
    const int ip = blockIdx.y >> 1;          // 0..27
    const int hg = blockIdx.y & 1;           // head group
    const int bz = blockIdx.z;
    const int i0 = 2 * ip;
    const int j0 = jt * 8;
    const int r0 = min(max(i0 - 3, 0), HW - KW);
    const int c0 = min(max(j0 - 3, 0), HW - KW);

    const int h = hg * 4 + wv;               // this wave's head

    // ---- prefetch Q A-frag + 7 K B-frags from global (hide under staging) --
    const int qpix = (bz * HW + i0 + (l15 >> 3)) * HW + j0 + (l15 & 7);
    bf16x8 aq = *(const bf16x8*)((const short*)Qg + (size_t)qpix * DIM + h * HD + hi * 8);

    bf16x8 kb[7];
    #pragma unroll
    for (int t = 0; t < 7; ++t) {
        const int key = t * 16 + l15;
        const int a = key / 14, c = key - a * 14;
        const int gi = min(r0 + a, HW - 1), gj = min(c0 + c, HW - 1);
        kb[t] = *(const bf16x8*)((const short*)Kg +
                 ((size_t)((bz * HW + gi) * HW + gj)) * DIM + h * HD + hi * 8);
    }

    // ---- stage V transposed: VshT[d'][key], d' = global dim - hg*128 -------
    {
        const int key = tid >> 1;            // 0..127
        const int dh  = tid & 1;             // 64-dim half of this head group
        const int a = key / 14, c = key - a * 14;
        const int gi = min(r0 + a, HW - 1), gj = min(c0 + c, HW - 1);
        const bool real = (key < UK);
        const short* srcV = (const short*)Vg +
            ((size_t)((bz * HW + gi) * HW + gj)) * DIM + hg * 128 + dh * 64;
        #pragma unroll
        for (int m = 0; m < 8; ++m) {
            const int d0 = dh * 64 + m * 8;
            bf16x8 vv = {0,0,0,0,0,0,0,0};
            if (real) vv = *(const bf16x8*)(srcV + m * 8);
            #pragma unroll
            for (int e = 0; e < 8; ++e) {
                const int d = d0 + e;        // d&7 == e
                *(short*)((char*)VshT + d * 256 + ((2 * key) ^ (e << 4))) = vv[e];
            }
        }
    }
    {   // zero Psh keys 112..127 (swizzled), per wave region
        const int p = (lane >> 2) & 15, m4 = lane & 3;
        const int k = UK + m4 * 4;
        char* dst = (char*)Psh + (wv * 16 + p) * 256 + ((2 * k) ^ (p << 4));
        *(int2*)dst = make_int2(0, 0);
    }
    __syncthreads();

    // per-lane pixel metadata for the 4 C-rows (pix = hi*4+r)
    int iv[4], jv[4], siv[4], sjv[4];
    #pragma unroll
    for (int r = 0; r < 4; ++r) {
        const int p = hi * 4 + r;
        iv[r] = i0 + (p >> 3);
        jv[r] = j0 + (p & 7);
        siv[r] = min(max(iv[r] - 3, 0), HW - KW);
        sjv[r] = min(max(jv[r] - 3, 0), HW - KW);
    }
    const f32x4 zf = {0.f, 0.f, 0.f, 0.f};

    // scores: 7 MFMA over key tiles
    f32x4 sacc[7];
    #pragma unroll
    for (int t = 0; t < 7; ++t)
        sacc[t] = __builtin_amdgcn_mfma_f32_16x16x32_bf16(aq, kb[t], zf, 0, 0, 0);

    // bias + mask -> sc[r][t]  (rpb from global, L1-hot)
    const float* rb = rpb + h * 169;
    float sc[4][7];
    #pragma unroll
    for (int t = 0; t < 7; ++t) {
        const int key = t * 16 + l15;
        const int a = key / 14, c = key - a * 14;
        const int ki = r0 + a, kj = c0 + c;
        #pragma unroll
        for (int r = 0; r < 4; ++r) {
            const bool ok = (ki >= siv[r]) & (ki <= siv[r] + 6) &
                            (kj >= sjv[r]) & (kj <= sjv[r] + 6);
            const int bidx = ok ? ((ki - iv[r] + 6) * 13 + (kj - jv[r] + 6)) : 0;
            const float s = sacc[t][r] + rb[bidx];
            sc[r][t] = ok ? s : -1e30f;
        }
    }

    // row max + exp + P store + sum (16-lane shfl reductions)
    float sm[4];
    #pragma unroll
    for (int r = 0; r < 4; ++r) {
        float m = sc[r][0];
        #pragma unroll
        for (int t = 1; t < 7; ++t) m = fmaxf(m, sc[r][t]);
        m = fmaxf(m, __shfl_xor(m, 1));
        m = fmaxf(m, __shfl_xor(m, 2));
        m = fmaxf(m, __shfl_xor(m, 4));
        m = fmaxf(m, __shfl_xor(m, 8));
        const int pix = hi * 4 + r;
        char* prow = (char*)Psh + (wv * 16 + pix) * 256;
        const int pswz = pix << 4;
        float s = 0.f;
        #pragma unroll
        for (int t = 0; t < 7; ++t) {
            const float e = __expf(sc[r][t] - m);
            s += e;
            const int key = t * 16 + l15;
            *(short*)(prow + ((2 * key) ^ pswz)) = f2bf(e);
        }
        s += __shfl_xor(s, 1);
        s += __shfl_xor(s, 2);
        s += __shfl_xor(s, 4);
        s += __shfl_xor(s, 8);
        sm[r] = s;
    }

    // PV: 4 ksteps x 2 dim-tiles; V via swizzled ds_read_b128 from VshT
    const int d0 = wv * 32 + l15;            // local dim row (d0&7 == l15&7)
    f32x4 o0 = zf, o1 = zf;
    #pragma unroll
    for (int kk = 0; kk < 4; ++kk) {
        bf16x8 pa = *(const bf16x8*)((char*)Psh + (wv * 16 + l15) * 256 +
                                     ((kk * 64 + hi * 16) ^ (l15 << 4)));
        const int koff = (kk * 64 + hi * 16) ^ ((l15 & 7) << 4);
        bf16x8 vb0 = *(const bf16x8*)((char*)VshT + d0 * 256 + koff);
        bf16x8 vb1 = *(const bf16x8*)((char*)VshT + (d0 + 16) * 256 + koff);
        o0 = __builtin_amdgcn_mfma_f32_16x16x32_bf16(pa, vb0, o0, 0, 0, 0);
        o1 = __builtin_amdgcn_mfma_f32_16x16x32_bf16(pa, vb1, o1, 0, 0, 0);
    }

    // epilogue: apply 1/sum, store f32
    #pragma unroll
    for (int r = 0; r < 4; ++r) {
        const float inv = 1.f / sm[r];
        const int pg = (bz * HW + iv[r]) * HW + jv[r];
        out[(size_t)pg * DIM + h * HD + l15]      = o0[r] * inv;
        out[(size_t)pg * DIM + h * HD + 16 + l15] = o1[r] * inv;
    }
}

extern "C" void kernel_launch(void* const* d_in, const int* in_sizes, int n_in,
                              void* d_out, int out_size, void* d_ws, size_t ws_size,
                              hipStream_t stream) {
    const float* hs = (const float*)d_in[0];
    const float* wq = (const float*)d_in[1];
    const float* bq = (const float*)d_in[2];
    const float* wk = (const float*)d_in[3];
    const float* bk = (const float*)d_in[4];
    const float* wv = (const float*)d_in[5];
    const float* bv = (const float*)d_in[6];
    const float* rpb = (const float*)d_in[7];

    short* Q   = (short*)d_ws;
    short* K   = Q + (size_t)NX;
    short* V   = K + (size_t)NX;
    short* Xb  = V + (size_t)NX;
    short* Wqb = Xb + (size_t)NX;
    short* Wkb = Wqb + (size_t)NW;
    short* Wvb = Wkb + (size_t)NW;

    cvt_kernel<<<(NX + 3 * NW) / (256 * 8), 256, 0, stream>>>(hs, wq, wk, wv,
                                                              Xb, Wqb, Wkb, Wvb);

    proj_kernel<<<dim3(NPIX / 64, 4, 3), 256, 0, stream>>>(
        Xb, Wqb, Wkb, Wvb, bq, bk, bv,
        (__hip_bfloat16*)Q, (__hip_bfloat16*)K, (__hip_bfloat16*)V);

    nattn_kernel<<<dim3(7, 56, 2), 256, 0, stream>>>(
        (const __hip_bfloat16*)Q, (const __hip_bfloat16*)K, (const __hip_bfloat16*)V,
        rpb, (float*)d_out);
}

// Round 7
// 40.051 us; speedup vs baseline: 1.0851x; 1.0851x over previous
//
#include <hip/hip_runtime.h>
#include <hip/hip_bf16.h>

typedef __attribute__((ext_vector_type(8))) short bf16x8;
typedef __attribute__((ext_vector_type(4))) float f32x4;

#define NPIX 6272          // 2*56*56
#define HW 56
#define HEADS 8
#define HD 32
#define KW 7
#define DIM 256
#define UK 112             // union keys: 8 rows x 14 cols
#define UKP 128            // padded keys
#define NX (NPIX * DIM)    // 1605632
#define NW (DIM * DIM)     // 65536

__device__ inline short f2bf(float f) {
    __hip_bfloat16 h = __float2bfloat16(f);
    return *(short*)&h;
}
__device__ inline float bf2f(short u) {
    union { unsigned int i; float f; } x;
    x.i = ((unsigned int)(unsigned short)u) << 16;
    return x.f;
}

// ---------------- f32 -> bf16 conversion pre-pass ---------------------------
__global__ __launch_bounds__(256) void cvt_kernel(
    const float* __restrict__ X,
    const float* __restrict__ Wq, const float* __restrict__ Wk, const float* __restrict__ Wv,
    short* __restrict__ Xb, short* __restrict__ Wqb,
    short* __restrict__ Wkb, short* __restrict__ Wvb)
{
    const size_t e0 = ((size_t)blockIdx.x * 256 + threadIdx.x) * 8;
    const float* src; short* dst; size_t off;
    if (e0 < NX)                { src = X;  dst = Xb;  off = e0; }
    else if (e0 < NX + NW)      { src = Wq; dst = Wqb; off = e0 - NX; }
    else if (e0 < NX + 2 * NW)  { src = Wk; dst = Wkb; off = e0 - NX - NW; }
    else                        { src = Wv; dst = Wvb; off = e0 - NX - 2 * NW; }
    float4 f0 = *(const float4*)(src + off);
    float4 f1 = *(const float4*)(src + off + 4);
    bf16x8 v;
    v[0]=f2bf(f0.x); v[1]=f2bf(f0.y); v[2]=f2bf(f0.z); v[3]=f2bf(f0.w);
    v[4]=f2bf(f1.x); v[5]=f2bf(f1.y); v[6]=f2bf(f1.z); v[7]=f2bf(f1.w);
    *(bf16x8*)(dst + off) = v;
}

// ---------------- Projection GEMM (bf16 in): Y = X @ W^T + b (* scale) ------
// All 16 global loads (8 W-staging + 8 A-frag) issued in one batch before the
// LDS writes; W writes wait only on the W loads (vmcnt age order), A arrives
// under the staging + barrier.
__global__ __launch_bounds__(256, 4) void proj_kernel(
    const short* __restrict__ Xb,
    const short* __restrict__ Wqb, const short* __restrict__ Wkb, const short* __restrict__ Wvb,
    const float* __restrict__ Bq, const float* __restrict__ Bk, const float* __restrict__ Bv,
    __hip_bfloat16* __restrict__ Qo, __hip_bfloat16* __restrict__ Ko, __hip_bfloat16* __restrict__ Vo)
{
    __shared__ short Wsh[64 * 256];   // 32KB, byte ^= ((col&31)<<4)

    const int tid  = threadIdx.x;
    const int wave = tid >> 6;
    const int lane = tid & 63;
    const int l15  = lane & 15;
    const int hi   = lane >> 4;

    const short* W; const float* Bi; __hip_bfloat16* Y; float scale;
    if (blockIdx.z == 0)      { W = Wqb; Bi = Bq; Y = Qo; scale = 0.17677669529663687f; }
    else if (blockIdx.z == 1) { W = Wkb; Bi = Bk; Y = Ko; scale = 1.0f; }
    else                      { W = Wvb; Bi = Bv; Y = Vo; scale = 1.0f; }

    // issue W staging loads (8)
    const int col = tid >> 2;
    const int k0  = (tid & 3) * 64;
    const short* wsrc = W + (size_t)(blockIdx.y * 64 + col) * DIM + k0;
    bf16x8 w8[8];
    #pragma unroll
    for (int m = 0; m < 8; ++m) w8[m] = *(const bf16x8*)(wsrc + m * 8);

    // issue A-frag loads (8) — in flight across staging + barrier
    const short* xrow = Xb + (size_t)(blockIdx.x * 64 + wave * 16 + l15) * DIM;
    bf16x8 a8[8];
    #pragma unroll
    for (int kk = 0; kk < 8; ++kk) a8[kk] = *(const bf16x8*)(xrow + kk * 32 + hi * 8);

    // write W -> LDS swizzled
    {
        char* row = (char*)Wsh + col * 512;
        const int swz = (col & 31) << 4;
        #pragma unroll
        for (int m = 0; m < 8; ++m)
            *(bf16x8*)(row + ((2 * (k0 + m * 8)) ^ swz)) = w8[m];
    }
    __syncthreads();

    f32x4 acc[4];
    #pragma unroll
    for (int c = 0; c < 4; ++c) acc[c] = (f32x4){0.f, 0.f, 0.f, 0.f};

    #pragma unroll
    for (int kk = 0; kk < 8; ++kk) {
        #pragma unroll
        for (int c = 0; c < 4; ++c) {
            const int bcol = c * 16 + l15;
            bf16x8 b = *(const bf16x8*)((char*)Wsh + bcol * 512 +
                                        ((kk * 64 + hi * 16) ^ ((bcol & 31) << 4)));
            acc[c] = __builtin_amdgcn_mfma_f32_16x16x32_bf16(a8[kk], b, acc[c], 0, 0, 0);
        }
    }

    #pragma unroll
    for (int c = 0; c < 4; ++c) {
        const int ocol = blockIdx.y * 64 + c * 16 + l15;
        const float bvv = Bi[ocol];
        #pragma unroll
        for (int r = 0; r < 4; ++r) {
            const int row = blockIdx.x * 64 + wave * 16 + hi * 4 + r;
            Y[(size_t)row * DIM + ocol] = __float2bfloat16((acc[c][r] + bvv) * scale);
        }
    }
}

// ---------------- Neighborhood attention, MFMA-tiled, head-split ------------
// block = (jt, ip|hg, b): 16 pixels x 4 heads; wave wv owns head hg*4+wv.
// LDS: VshT 32K + Psh 16K + rpbs(bf16) 2.7K = 51.9K -> 3 blocks/CU.
// All global loads batched; rpb gathered from LDS; V staged via conflict-free
// key-pair-packed b32 writes.
__global__ __launch_bounds__(256, 3) void nattn_kernel(
    const __hip_bfloat16* __restrict__ Qg,   // [NPIX][256] bf16 ws
    const __hip_bfloat16* __restrict__ Kg,
    const __hip_bfloat16* __restrict__ Vg,
    const float* __restrict__ rpb,           // [8][13][13] f32
    float* __restrict__ out)                 // [NPIX][256] f32
{
    __shared__ short VshT[128 * UKP];            // 32768 B: [d'][key], byte ^= ((d'&7)<<4)
    __shared__ short Psh[4 * 16 * UKP];          // 16384 B: byte ^= (pix<<4)
    __shared__ __align__(16) short rpbs[8 * 169]; // 2704 B bf16

    const int tid  = threadIdx.x;
    const int wv   = tid >> 6;
    const int lane = tid & 63;
    const int l15  = lane & 15;
    const int hi   = lane >> 4;

    const int jt = blockIdx.x;               // 0..6
    const int ip = blockIdx.y >> 1;          // 0..27
    const int hg = blockIdx.y & 1;           // head group
    const int bz = blockIdx.z;
    const int i0 = 2 * ip;
    const int j0 = jt * 8;
    const int r0 = min(max(i0 - 3, 0), HW - KW);
    const int c0 = min(max(j0 - 3, 0), HW - KW);

    const int h = hg * 4 + wv;               // this wave's head

    // ---- batch-issue ALL staging global loads ------------------------------
    // V: thread owns key pair (2k, 2k+1) x 32 dims (dblock)
    const int k2   = tid & 63;               // key pair index
    const int dblk = tid >> 6;               // 0..3 -> dims dblk*32..+31
    const int keyL = 2 * k2, keyR = 2 * k2 + 1;
    const int aL = keyL / 14, cL = keyL - aL * 14;
    const int aR = keyR / 14, cR = keyR - aR * 14;
    const int giL = min(r0 + aL, HW - 1), gjL = min(c0 + cL, HW - 1);
    const int giR = min(r0 + aR, HW - 1), gjR = min(c0 + cR, HW - 1);
    const short* srcL = (const short*)Vg + ((size_t)((bz * HW + giL) * HW + gjL)) * DIM + hg * 128 + dblk * 32;
    const short* srcR = (const short*)Vg + ((size_t)((bz * HW + giR) * HW + gjR)) * DIM + hg * 128 + dblk * 32;
    bf16x8 vL[4], vR[4];
    #pragma unroll
    for (int m = 0; m < 4; ++m) {
        vL[m] = (keyL < UK) ? *(const bf16x8*)(srcL + m * 8) : (bf16x8){0,0,0,0,0,0,0,0};
        vR[m] = (keyR < UK) ? *(const bf16x8*)(srcR + m * 8) : (bf16x8){0,0,0,0,0,0,0,0};
    }

    // Q A-frag (in flight across staging barrier)
    const int qpix = (bz * HW + i0 + (l15 >> 3)) * HW + j0 + (l15 & 7);
    bf16x8 aq = *(const bf16x8*)((const short*)Qg + (size_t)qpix * DIM + h * HD + hi * 8);

    // rpb loads (338 float4 total)
    const float4* rpb4 = (const float4*)rpb;
    float4 rv0 = rpb4[tid];
    float4 rv1 = (tid < 338 - 256) ? rpb4[tid + 256] : (float4){0.f,0.f,0.f,0.f};

    // ---- LDS writes --------------------------------------------------------
    // V transposed, key-pair packed b32: addr = d*256 + ((4*k2) ^ ((d&7)<<4))
    #pragma unroll
    for (int m = 0; m < 4; ++m) {
        #pragma unroll
        for (int e = 0; e < 8; ++e) {
            const int d = dblk * 32 + m * 8 + e;          // d&7 == e
            const int w = ((int)(unsigned short)vL[m][e]) | ((int)vR[m][e] << 16);
            *(int*)((char*)VshT + d * 256 + ((4 * k2) ^ (e << 4))) = w;
        }
    }
    // rpb -> LDS bf16
    *(short4*)(&rpbs[tid * 4]) = make_short4(f2bf(rv0.x), f2bf(rv0.y), f2bf(rv0.z), f2bf(rv0.w));
    if (tid < 338 - 256)
        *(short4*)(&rpbs[(tid + 256) * 4]) = make_short4(f2bf(rv1.x), f2bf(rv1.y), f2bf(rv1.z), f2bf(rv1.w));
    {   // zero Psh keys 112..127 (swizzled), per wave region
        const int p = (lane >> 2) & 15, m4 = lane & 3;
        const int k = UK + m4 * 4;
        char* dst = (char*)Psh + (wv * 16 + p) * 256 + ((2 * k) ^ (p << 4));
        *(int2*)dst = make_int2(0, 0);
    }
    __syncthreads();

    // per-lane pixel metadata for the 4 C-rows (pix = hi*4+r)
    int iv[4], jv[4], bb[4], uai[4], ucj[4];
    #pragma unroll
    for (int r = 0; r < 4; ++r) {
        const int p = hi * 4 + r;
        iv[r] = i0 + (p >> 3);
        jv[r] = j0 + (p & 7);
        const int siv = min(max(iv[r] - 3, 0), HW - KW);
        const int sjv = min(max(jv[r] - 3, 0), HW - KW);
        bb[r]  = (r0 - iv[r] + 6) * 13 + (c0 - jv[r] + 6);
        uai[r] = siv - r0;
        ucj[r] = sjv - c0;
    }
    const f32x4 zf = {0.f, 0.f, 0.f, 0.f};

    // scores: batch-issue 7 K B-frag loads, then 7 MFMAs
    f32x4 sacc[7];
    {
        bf16x8 kb[7];
        #pragma unroll
        for (int t = 0; t < 7; ++t) {
            const int key = t * 16 + l15;
            const int a = key / 14, c = key - a * 14;
            const int gi = min(r0 + a, HW - 1), gj = min(c0 + c, HW - 1);
            kb[t] = *(const bf16x8*)((const short*)Kg +
                     ((size_t)((bz * HW + gi) * HW + gj)) * DIM + h * HD + hi * 8);
        }
        #pragma unroll
        for (int t = 0; t < 7; ++t)
            sacc[t] = __builtin_amdgcn_mfma_f32_16x16x32_bf16(aq, kb[t], zf, 0, 0, 0);
    }

    // bias + mask -> sc[r][t]  (bias from LDS bf16)
    const short* rbh = rpbs + h * 169;
    int aA[7], cA[7], a13[7];
    #pragma unroll
    for (int t = 0; t < 7; ++t) {
        const int key = t * 16 + l15;
        aA[t] = key / 14;
        cA[t] = key - aA[t] * 14;
        a13[t] = aA[t] * 13 + cA[t];
    }
    float sc[4][7];
    #pragma unroll
    for (int t = 0; t < 7; ++t) {
        #pragma unroll
        for (int r = 0; r < 4; ++r) {
            const bool ok = ((unsigned)(aA[t] - uai[r]) <= 6u) &
                            ((unsigned)(cA[t] - ucj[r]) <= 6u);
            const float s = sacc[t][r] + bf2f(rbh[bb[r] + a13[t]]);
            sc[r][t] = ok ? s : -1e30f;
        }
    }

    // row max + exp + P store + sum (16-lane shfl reductions)
    float sm[4];
    #pragma unroll
    for (int r = 0; r < 4; ++r) {
        float m = sc[r][0];
        #pragma unroll
        for (int t = 1; t < 7; ++t) m = fmaxf(m, sc[r][t]);
        m = fmaxf(m, __shfl_xor(m, 1));
        m = fmaxf(m, __shfl_xor(m, 2));
        m = fmaxf(m, __shfl_xor(m, 4));
        m = fmaxf(m, __shfl_xor(m, 8));
        const int pix = hi * 4 + r;
        char* prow = (char*)Psh + (wv * 16 + pix) * 256;
        const int pswz = pix << 4;
        float s = 0.f;
        #pragma unroll
        for (int t = 0; t < 7; ++t) {
            const float e = __expf(sc[r][t] - m);
            s += e;
            const int key = t * 16 + l15;
            *(short*)(prow + ((2 * key) ^ pswz)) = f2bf(e);
        }
        s += __shfl_xor(s, 1);
        s += __shfl_xor(s, 2);
        s += __shfl_xor(s, 4);
        s += __shfl_xor(s, 8);
        sm[r] = s;
    }

    // PV: 4 ksteps x 2 dim-tiles; V via swizzled ds_read_b128 from VshT
    const int d0 = wv * 32 + l15;            // local dim row (d0&7 == l15&7)
    f32x4 o0 = zf, o1 = zf;
    #pragma unroll
    for (int kk = 0; kk < 4; ++kk) {
        bf16x8 pa = *(const bf16x8*)((char*)Psh + (wv * 16 + l15) * 256 +
                                     ((kk * 64 + hi * 16) ^ (l15 << 4)));
        const int koff = (kk * 64 + hi * 16) ^ ((l15 & 7) << 4);
        bf16x8 vb0 = *(const bf16x8*)((char*)VshT + d0 * 256 + koff);
        bf16x8 vb1 = *(const bf16x8*)((char*)VshT + (d0 + 16) * 256 + koff);
        o0 = __builtin_amdgcn_mfma_f32_16x16x32_bf16(pa, vb0, o0, 0, 0, 0);
        o1 = __builtin_amdgcn_mfma_f32_16x16x32_bf16(pa, vb1, o1, 0, 0, 0);
    }

    // epilogue: apply 1/sum, store f32
    #pragma unroll
    for (int r = 0; r < 4; ++r) {
        const float inv = 1.f / sm[r];
        const int pg = (bz * HW + iv[r]) * HW + jv[r];
        out[(size_t)pg * DIM + h * HD + l15]      = o0[r] * inv;
        out[(size_t)pg * DIM + h * HD + 16 + l15] = o1[r] * inv;
    }
}

extern "C" void kernel_launch(void* const* d_in, const int* in_sizes, int n_in,
                              void* d_out, int out_size, void* d_ws, size_t ws_size,
                              hipStream_t stream) {
    const float* hs = (const float*)d_in[0];
    const float* wq = (const float*)d_in[1];
    const float* bq = (const float*)d_in[2];
    const float* wk = (const float*)d_in[3];
    const float* bk = (const float*)d_in[4];
    const float* wv = (const float*)d_in[5];
    const float* bv = (const float*)d_in[6];
    const float* rpb = (const float*)d_in[7];

    short* Q   = (short*)d_ws;
    short* K   = Q + (size_t)NX;
    short* V   = K + (size_t)NX;
    short* Xb  = V + (size_t)NX;
    short* Wqb = Xb + (size_t)NX;
    short* Wkb = Wqb + (size_t)NW;
    short* Wvb = Wkb + (size_t)NW;

    cvt_kernel<<<(NX + 3 * NW) / (256 * 8), 256, 0, stream>>>(hs, wq, wk, wv,
                                                              Xb, Wqb, Wkb, Wvb);

    proj_kernel<<<dim3(NPIX / 64, 4, 3), 256, 0, stream>>>(
        Xb, Wqb, Wkb, Wvb, bq, bk, bv,
        (__hip_bfloat16*)Q, (__hip_bfloat16*)K, (__hip_bfloat16*)V);

    nattn_kernel<<<dim3(7, 56, 2), 256, 0, stream>>>(
        (const __hip_bfloat16*)Q, (const __hip_bfloat16*)K, (const __hip_bfloat16*)V,
        rpb, (float*)d_out);
}